// Round 4
// baseline (426.640 us; speedup 1.0000x reference)
//
#include <hip/hip_runtime.h>
#include <stdint.h>

// Problem constants (reference: B=8, Q=2048, K=2048, D=512)
#define BB 8
#define QQ 2048
#define KK 2048
#define DD 512

typedef _Float16 f16x8 __attribute__((ext_vector_type(8)));
typedef float f32x4 __attribute__((ext_vector_type(4)));

__device__ __forceinline__ unsigned short f2h(float f) {
    union { _Float16 h; unsigned short u; } x;
    x.h = (_Float16)f;
    return x.u;
}
__device__ __forceinline__ float h2f(unsigned short u) {
    union { unsigned short u; _Float16 h; } x;
    x.u = u;
    return (float)x.h;
}

// async global->LDS, 16 B per lane; lds is wave-uniform base, HW scatters
// lane l to lds + l*16 (m97/m104 semantics).
__device__ __forceinline__ void async16(const unsigned short* g, unsigned short* l) {
    __builtin_amdgcn_global_load_lds(
        (const __attribute__((address_space(1))) unsigned int*)g,
        (__attribute__((address_space(3))) unsigned int*)l, 16, 0, 0);
}

// ---------------------------------------------------------------------------
// fp32 -> fp16 convert, 8 elems/thread
// ---------------------------------------------------------------------------
__global__ __launch_bounds__(256) void cvt_f32_f16(const float* __restrict__ in,
                                                   unsigned short* __restrict__ out) {
    size_t i = ((size_t)blockIdx.x * 256 + threadIdx.x) * 8;
    float4 a = *(const float4*)(in + i);
    float4 b = *(const float4*)(in + i + 4);
    uint4 u;
    u.x = (unsigned)f2h(a.x) | ((unsigned)f2h(a.y) << 16);
    u.y = (unsigned)f2h(a.z) | ((unsigned)f2h(a.w) << 16);
    u.z = (unsigned)f2h(b.x) | ((unsigned)f2h(b.y) << 16);
    u.w = (unsigned)f2h(b.z) | ((unsigned)f2h(b.w) << 16);
    *(uint4*)(out + i) = u;
}

// ---------------------------------------------------------------------------
// Tiled transpose + convert: in[R][C] fp32 -> out[C][R] fp16 (32x32 tiles)
// ---------------------------------------------------------------------------
__global__ __launch_bounds__(256) void transpose_cvt(const float* __restrict__ in,
                                                     unsigned short* __restrict__ out,
                                                     int R, int C, long inB, long outB) {
    __shared__ float t[32][33];
    const float* ip = in + (size_t)blockIdx.z * inB;
    unsigned short* op = out + (size_t)blockIdx.z * outB;
    int x = threadIdx.x & 31, y0 = threadIdx.x >> 5;   // 32 x 8
    int c0 = blockIdx.x * 32, r0 = blockIdx.y * 32;
#pragma unroll
    for (int i = 0; i < 32; i += 8)
        t[y0 + i][x] = ip[(size_t)(r0 + y0 + i) * C + c0 + x];
    __syncthreads();
#pragma unroll
    for (int i = 0; i < 32; i += 8)
        op[(size_t)(c0 + y0 + i) * R + r0 + x] = f2h(t[x][y0 + i]);
}

// ---------------------------------------------------------------------------
// NT GEMM: C[m,n] = sum_k A[m,k]*B[n,k], 128x128 tile, BK=32, f16 MFMA,
// async global_load_lds staging on both operands.
// OUTM 0: plain f16 out (qW)
// OUTM 1: expS epilogue: e = mask ? exp(acc*scale) : 0 -> f16 out,
//         per-row sums accumulated into `sums` via atomicAdd (scores)
// OUTM 2: fp32 out scaled by 1/sums[row] (context), and during the K-loop
//         each block writes its k-slice of dist = As * (1/sums[row]) (fp32)
//         straight from the staged LDS tile — replaces the normalize pass.
// ---------------------------------------------------------------------------
template <int OUTM>
__global__ __launch_bounds__(256) void gemm_bt(const unsigned short* __restrict__ Aall,
                                               const unsigned short* __restrict__ Ball,
                                               void* __restrict__ Call,
                                               const int* __restrict__ maskAll,
                                               float* __restrict__ sums,
                                               float* __restrict__ dist,
                                               int Kred, int lda, int ldb, int ldc,
                                               long aStride, long bStride, long cStride,
                                               int maskStride, float scale) {
    const int b = blockIdx.z;
    const int m0 = blockIdx.y * 128;
    const int n0 = blockIdx.x * 128;

    __shared__ unsigned short As[128 * 32];
    __shared__ unsigned short Bs[128 * 32];

    const int tid = threadIdx.x;
    const int lane = tid & 63, wave = tid >> 6;
    const int wm = wave >> 1, wn = wave & 1;
    const int lrow = lane & 15, quad = lane >> 4;

    // async staging: call j covers rows j*64 + tid>>2, col (tid&3)*8 (16 B)
    const int ar = tid >> 2, ac = (tid & 3) * 8;

    const unsigned short* Ab = Aall + (size_t)b * aStride + (size_t)m0 * lda;
    const unsigned short* Bb = Ball + (size_t)b * bStride + (size_t)n0 * ldb;
    unsigned short* AsW = As + wave * 512;   // wave-uniform async dst
    unsigned short* BsW = Bs + wave * 512;

    // context path: per-thread row for the fused dist write (2 threads/row)
    float invRow = 0.f;
    if constexpr (OUTM == 2)
        invRow = 1.0f / sums[(size_t)b * QQ + m0 + (tid >> 1)];

    f32x4 acc[4][4];
#pragma unroll
    for (int mi = 0; mi < 4; mi++)
#pragma unroll
        for (int ni = 0; ni < 4; ni++)
            acc[mi][ni] = (f32x4){0.f, 0.f, 0.f, 0.f};

    for (int kk = 0; kk < Kred; kk += 32) {
#pragma unroll
        for (int j = 0; j < 2; j++)
            async16(Ab + (size_t)(j * 64 + ar) * lda + kk + ac, AsW + j * 2048);
#pragma unroll
        for (int j = 0; j < 2; j++)
            async16(Bb + (size_t)(j * 64 + ar) * ldb + kk + ac, BsW + j * 2048);
        __syncthreads();

        if constexpr (OUTM == 2) {
            // fused normalize: block with n-index j owns dist k-slice
            // [j*512, j*512+512); write it from the staged As tile.
            if ((kk >> 9) == (int)blockIdx.x) {
                const int r = tid >> 1, c = (tid & 1) * 16;
                f16x8 h0 = *(const f16x8*)&As[r * 32 + c];
                f16x8 h1 = *(const f16x8*)&As[r * 32 + c + 8];
                float* dp = dist + ((size_t)b * QQ + m0 + r) * KK + kk + c;
                float4 o;
                o.x = (float)h0[0] * invRow; o.y = (float)h0[1] * invRow;
                o.z = (float)h0[2] * invRow; o.w = (float)h0[3] * invRow;
                *(float4*)dp = o;
                o.x = (float)h0[4] * invRow; o.y = (float)h0[5] * invRow;
                o.z = (float)h0[6] * invRow; o.w = (float)h0[7] * invRow;
                *(float4*)(dp + 4) = o;
                o.x = (float)h1[0] * invRow; o.y = (float)h1[1] * invRow;
                o.z = (float)h1[2] * invRow; o.w = (float)h1[3] * invRow;
                *(float4*)(dp + 8) = o;
                o.x = (float)h1[4] * invRow; o.y = (float)h1[5] * invRow;
                o.z = (float)h1[6] * invRow; o.w = (float)h1[7] * invRow;
                *(float4*)(dp + 12) = o;
            }
        }

        f16x8 af[4], bfr[4];
#pragma unroll
        for (int i = 0; i < 4; i++)
            af[i] = *(const f16x8*)&As[(wm * 64 + i * 16 + lrow) * 32 + quad * 8];
#pragma unroll
        for (int i = 0; i < 4; i++)
            bfr[i] = *(const f16x8*)&Bs[(wn * 64 + i * 16 + lrow) * 32 + quad * 8];

#pragma unroll
        for (int mi = 0; mi < 4; mi++)
#pragma unroll
            for (int ni = 0; ni < 4; ni++)
                acc[mi][ni] = __builtin_amdgcn_mfma_f32_16x16x32_f16(af[mi], bfr[ni],
                                                                     acc[mi][ni], 0, 0, 0);
        __syncthreads();
    }

    // ---- epilogue ----
#pragma unroll
    for (int mi = 0; mi < 4; mi++) {
        const int gm = m0 + wm * 64 + mi * 16 + quad * 4;
        if constexpr (OUTM == 0) {
            unsigned short* C = (unsigned short*)Call + (size_t)b * cStride;
#pragma unroll
            for (int ni = 0; ni < 4; ni++) {
                int gn = n0 + wn * 64 + ni * 16 + lrow;
#pragma unroll
                for (int r = 0; r < 4; r++)
                    C[(size_t)(gm + r) * ldc + gn] = f2h(acc[mi][ni][r]);
            }
        } else if constexpr (OUTM == 1) {
            unsigned short* C = (unsigned short*)Call + (size_t)b * cStride;
            const int* mk = maskAll + (size_t)b * maskStride;
            float ps[4] = {0.f, 0.f, 0.f, 0.f};
#pragma unroll
            for (int ni = 0; ni < 4; ni++) {
                int gn = n0 + wn * 64 + ni * 16 + lrow;
                bool keep = mk[gn] != 0;
#pragma unroll
                for (int r = 0; r < 4; r++) {
                    float e = keep ? __expf(acc[mi][ni][r] * scale) : 0.f;
                    C[(size_t)(gm + r) * ldc + gn] = f2h(e);
                    ps[r] += e;
                }
            }
            // reduce across the 16 lanes sharing this quad's rows
#pragma unroll
            for (int off = 1; off < 16; off <<= 1)
#pragma unroll
                for (int r = 0; r < 4; r++) ps[r] += __shfl_xor(ps[r], off);
            if (lrow == 0) {
                float* s = sums + (size_t)b * QQ;
#pragma unroll
                for (int r = 0; r < 4; r++) atomicAdd(&s[gm + r], ps[r]);
            }
        } else {
            float* C = (float*)Call + (size_t)b * cStride;
            const float* s = sums + (size_t)b * QQ;
            float iv[4];
#pragma unroll
            for (int r = 0; r < 4; r++) iv[r] = 1.0f / s[gm + r];
#pragma unroll
            for (int ni = 0; ni < 4; ni++) {
                int gn = n0 + wn * 64 + ni * 16 + lrow;
#pragma unroll
                for (int r = 0; r < 4; r++)
                    C[(size_t)(gm + r) * ldc + gn] = acc[mi][ni][r] * iv[r];
            }
        }
    }
}

// ---------------------------------------------------------------------------
extern "C" void kernel_launch(void* const* d_in, const int* in_sizes, int n_in,
                              void* d_out, int out_size, void* d_ws, size_t ws_size,
                              hipStream_t stream) {
    const float* q    = (const float*)d_in[0];   // [B,Q,D]
    const float* k    = (const float*)d_in[1];   // [B,K,D]
    const float* v    = (const float*)d_in[2];   // [B,K,D]
    const int*   mask = (const int*)d_in[3];     // [B,K]
    const float* W    = (const float*)d_in[4];   // [D,D]

    float* ctx  = (float*)d_out;                           // [B,Q,D]
    float* dist = ctx + (size_t)BB * QQ * DD;              // [B,Q,K]

    // workspace layout (f16 = unsigned short), ~135 MiB
    unsigned short* ws  = (unsigned short*)d_ws;
    unsigned short* Wt  = ws;                                   // [D][D]   (W^T)
    unsigned short* Qh  = Wt + (size_t)DD * DD;                 // [B][Q][D]
    unsigned short* Kh  = Qh + (size_t)BB * QQ * DD;            // [B][K][D]
    unsigned short* Vt  = Kh + (size_t)BB * KK * DD;            // [B][D][K] (V^T)
    unsigned short* qWh = Vt + (size_t)BB * DD * KK;            // [B][Q][D]
    unsigned short* Sc  = qWh + (size_t)BB * QQ * DD;           // [B][Q][K] expS f16
    float* sums = (float*)(Sc + (size_t)BB * QQ * KK);          // [B][Q]

    const float scale = 0.044194173824159216f;  // 1/sqrt(512)

    // 0) zero the row-sum accumulators (graph-capture-legal async memset)
    hipMemsetAsync(sums, 0, (size_t)BB * QQ * sizeof(float), stream);
    // 1) W -> W^T f16
    transpose_cvt<<<dim3(DD / 32, DD / 32, 1), 256, 0, stream>>>(W, Wt, DD, DD, 0, 0);
    // 2) query, key -> f16
    cvt_f32_f16<<<dim3((BB * QQ * DD / 8) / 256), 256, 0, stream>>>(q, Qh);
    cvt_f32_f16<<<dim3((BB * KK * DD / 8) / 256), 256, 0, stream>>>(k, Kh);
    // 3) value -> V^T f16
    transpose_cvt<<<dim3(DD / 32, KK / 32, BB), 256, 0, stream>>>(
        v, Vt, KK, DD, (long)KK * DD, (long)DD * KK);
    // 4) qW[b] = Q[b] @ W: M=Q, N=D, Kred=D -> f16
    gemm_bt<0><<<dim3(DD / 128, QQ / 128, BB), 256, 0, stream>>>(
        Qh, Wt, qWh, nullptr, nullptr, nullptr, DD, DD, DD, DD,
        (long)QQ * DD, 0, (long)QQ * DD, 0, 0.f);
    // 5) expS[b] = exp(scale * qW[b] @ key[b]^T) (masked->0) + row sums
    gemm_bt<1><<<dim3(KK / 128, QQ / 128, BB), 256, 0, stream>>>(
        qWh, Kh, Sc, mask, sums, nullptr, DD, DD, DD, KK,
        (long)QQ * DD, (long)KK * DD, (long)QQ * KK, KK, scale);
    // 6) context[b] = (expS[b] @ value[b]) / rowsum, fused dist = expS/rowsum
    gemm_bt<2><<<dim3(DD / 128, QQ / 128, BB), 256, 0, stream>>>(
        Sc, Vt, ctx, nullptr, sums, dist, KK, KK, KK, DD,
        (long)QQ * KK, (long)DD * KK, (long)QQ * DD, 0, 0.f);
}